// Round 3
// baseline (660.769 us; speedup 1.0000x reference)
//
#include <hip/hip_runtime.h>

#define FCn 64      // FC
#define NCOL 256    // padded logical t-columns (224 used)
#define TEB 64      // edges per block
#define LDP 68      // padded LDS row stride (floats)

// ---------------- precompute: fold s, rad_w2/rad_b2, proj_w*, 0.25 into M (64x224), cvec(224), b0s(128)
__global__ __launch_bounds__(256) void precomp_kernel(
    const float* __restrict__ exp_w, const float* __restrict__ exp_b,
    const float* __restrict__ rad_w2, const float* __restrict__ rad_b2,
    const float* __restrict__ proj_w0, const float* __restrict__ proj_b0,
    const float* __restrict__ proj_w1, const float* __restrict__ proj_w2,
    float* __restrict__ Mg, float* __restrict__ cvec, float* __restrict__ b0s)
{
    const int r = blockIdx.x;   // 0..63 -> M row r; 64 -> cvec/b0s
    const int c = threadIdx.x;  // 0..255
    const float* wrow = (r < FCn) ? (rad_w2 + (long long)r * 384) : rad_b2;
    float acc = 0.f;
    if (c < 128) {
        for (int q = 0; q < 128; ++q)
            acc += wrow[q] * (exp_w[q] + exp_b[q]) * proj_w0[q * 128 + c];
    } else if (c < 192) {
        const int d = c - 128;
        for (int q = 0; q < 128; ++q)
            acc += wrow[128 + q] * (exp_w[q] + exp_b[q]) * proj_w1[q * 64 + d];
    } else if (c < 224) {
        const int d = c - 192;
        for (int q = 0; q < 128; ++q)
            acc += wrow[256 + q] * (exp_w[q] + exp_b[q]) * proj_w2[q * 32 + d];
    }
    acc *= 0.25f;  // 1/sqrt(AVG_AGG)
    if (r < FCn) {
        Mg[r * NCOL + c] = acc;
    } else {
        cvec[c] = acc;
        if (c < 128) b0s[c] = 0.25f * proj_b0[c];
    }
}

// ---------------- CSR build
__global__ __launch_bounds__(256) void hist_kernel(const int* __restrict__ dst, int* __restrict__ cnt, int E)
{
    for (int e = blockIdx.x * 256 + threadIdx.x; e < E; e += gridDim.x * 256)
        atomicAdd(&cnt[dst[e]], 1);
}

__global__ __launch_bounds__(256) void scan_kernel(const int* __restrict__ cnt, int* __restrict__ off,
                                                   int* __restrict__ cur, int Nn, int Etot)
{
    __shared__ int part[256];
    __shared__ int spart[257];
    const int t = threadIdx.x;
    const int per = (Nn + 255) / 256;
    int s = 0;
    for (int i = 0; i < per; ++i) {
        const int idx = t * per + i;
        if (idx < Nn) s += cnt[idx];
    }
    part[t] = s;
    __syncthreads();
    if (t == 0) {
        int run = 0;
        spart[0] = 0;
        for (int i = 0; i < 256; ++i) { run += part[i]; spart[i + 1] = run; }
    }
    __syncthreads();
    int run = spart[t];
    for (int i = 0; i < per; ++i) {
        const int idx = t * per + i;
        if (idx < Nn) { off[idx] = run; cur[idx] = run; run += cnt[idx]; }
    }
    if (t == 0) off[Nn] = Etot;
}

__global__ __launch_bounds__(256) void scatter_kernel(const int* __restrict__ dst, int* __restrict__ cur,
                                                      int* __restrict__ eids, int* __restrict__ dsts, int E)
{
    for (int e = blockIdx.x * 256 + threadIdx.x; e < E; e += gridDim.x * 256) {
        const int d = dst[e];
        const int pos = atomicAdd(&cur[d], 1);
        eids[pos] = e;
        dsts[pos] = d;
    }
}

// ---------------- flush helper: 15 atomics covering one node's 480 cols (per eg-group wavefront slice)
__device__ inline void flushRun(float* __restrict__ out, int dst, int cg,
                                const float* run, const float* b0v, int runLen)
{
    float* ob = out + (long long)dst * 480;
    const float fl = (float)runLen;
    #pragma unroll
    for (int j = 0; j < 4; ++j)
        atomicAdd(ob + cg + 32 * j, fmaf(fl, b0v[j], run[j]));
    atomicAdd(ob + 128 + cg * 3 + 0,        run[4]);
    atomicAdd(ob + 128 + cg * 3 + 1,        run[5]);
    atomicAdd(ob + 128 + cg * 3 + 2,        run[6]);
    atomicAdd(ob + 128 + (cg + 32) * 3 + 0, run[7]);
    atomicAdd(ob + 128 + (cg + 32) * 3 + 1, run[8]);
    atomicAdd(ob + 128 + (cg + 32) * 3 + 2, run[9]);
    #pragma unroll
    for (int r = 0; r < 5; ++r)
        atomicAdd(ob + 320 + cg * 5 + r, run[10 + r]);
}

// ---------------- fused kernel: 64 dst-sorted edges / block, register-run accumulation, atomic flush per run
__global__ __launch_bounds__(256, 3) void fused_kernel(
    const float* __restrict__ edge_attr,    // E x 9
    const float* __restrict__ edge_scalars, // E x 64
    const int*   __restrict__ eids,         // E (sorted positions -> edge id)
    const int*   __restrict__ dsts,         // E (sorted positions -> dst node)
    const float* __restrict__ rad_w1,       // 64 x 64
    const float* __restrict__ rad_b1,       // 64
    const float* __restrict__ rad_gamma,    // 64
    const float* __restrict__ rad_beta,     // 64
    const float* __restrict__ Mg,           // 64 x 256 (ws)
    const float* __restrict__ cvec,         // 256 (ws)
    const float* __restrict__ b0s,          // 128 (ws)
    float* __restrict__ out,                // N x 480 (pre-zeroed)
    int E)
{
    __shared__ float XT[FCn * LDP];   // [k][e]; reused as Hs^T after LN
    __shared__ float Hb[TEB * LDP];   // [e][c]
    __shared__ float Ea[TEB][12];     // staged edge_attr rows
    __shared__ int   eids_l[TEB];
    __shared__ int   dsts_l[TEB];
    const int t = threadIdx.x;
    const int p0 = blockIdx.x * TEB;

    if (t < TEB) {
        const int p = p0 + t;
        eids_l[t] = (p < E) ? eids[p] : -1;
        dsts_l[t] = (p < E) ? dsts[p] : -1;
    }
    __syncthreads();

    // ---- stage X^T (gathered rows, 256B-aligned) + Ea
    #pragma unroll
    for (int i = 0; i < 4; ++i) {
        const int idx = i * 256 + t;
        const int e  = idx >> 4;
        const int kq = idx & 15;
        const int eid = eids_l[e];
        float4 v = make_float4(0.f, 0.f, 0.f, 0.f);
        if (eid >= 0) v = *(const float4*)(edge_scalars + (long long)eid * FCn + kq * 4);
        XT[(kq * 4 + 0) * LDP + e] = v.x;
        XT[(kq * 4 + 1) * LDP + e] = v.y;
        XT[(kq * 4 + 2) * LDP + e] = v.z;
        XT[(kq * 4 + 3) * LDP + e] = v.w;
    }
    #pragma unroll
    for (int i = 0; i < 3; ++i) {
        const int idx = i * 256 + t;
        if (idx < TEB * 9) {
            const int e = idx / 9, j = idx - e * 9;
            const int eid = eids_l[e];
            Ea[e][j] = (eid >= 0) ? edge_attr[(long long)eid * 9 + j] : 0.f;
        }
    }
    __syncthreads();

    // ---- GEMM1: H = X @ W1 + b1 (64e x 64c), per-thread 4x4
    {
        const int eg = t >> 4, cg = t & 15;
        float a[4][4];
        #pragma unroll
        for (int i = 0; i < 4; ++i)
            #pragma unroll
            for (int j = 0; j < 4; ++j) a[i][j] = 0.f;
        for (int k = 0; k < FCn; ++k) {
            const float4 xv = *(const float4*)&XT[k * LDP + eg * 4];
            const float4 wv = *(const float4*)&rad_w1[k * FCn + cg * 4];
            const float xe[4] = {xv.x, xv.y, xv.z, xv.w};
            const float wc[4] = {wv.x, wv.y, wv.z, wv.w};
            #pragma unroll
            for (int i = 0; i < 4; ++i)
                #pragma unroll
                for (int j = 0; j < 4; ++j)
                    a[i][j] += xe[i] * wc[j];
        }
        const float4 bv = *(const float4*)&rad_b1[cg * 4];
        const float bb[4] = {bv.x, bv.y, bv.z, bv.w};
        #pragma unroll
        for (int i = 0; i < 4; ++i) {
            float4 o;
            o.x = a[i][0] + bb[0]; o.y = a[i][1] + bb[1];
            o.z = a[i][2] + bb[2]; o.w = a[i][3] + bb[3];
            *(float4*)&Hb[(eg * 4 + i) * LDP + cg * 4] = o;
        }
    }
    __syncthreads();

    // ---- LayerNorm + silu, transpose into XT
    if (t < TEB) {
        const float4* hrow = (const float4*)&Hb[t * LDP];
        float4 r[16];
        float s1 = 0.f, s2 = 0.f;
        #pragma unroll
        for (int i = 0; i < 16; ++i) {
            r[i] = hrow[i];
            s1 += r[i].x + r[i].y + r[i].z + r[i].w;
            s2 += r[i].x * r[i].x + r[i].y * r[i].y + r[i].z * r[i].z + r[i].w * r[i].w;
        }
        const float mu  = s1 * (1.f / 64.f);
        const float var = s2 * (1.f / 64.f) - mu * mu;
        const float rs  = rsqrtf(var + 1e-5f);
        #pragma unroll
        for (int i = 0; i < 16; ++i) {
            const float4 g = *(const float4*)&rad_gamma[i * 4];
            const float4 b = *(const float4*)&rad_beta[i * 4];
            const float hv[4] = {r[i].x, r[i].y, r[i].z, r[i].w};
            const float gv[4] = {g.x, g.y, g.z, g.w};
            const float bv2[4] = {b.x, b.y, b.z, b.w};
            #pragma unroll
            for (int j = 0; j < 4; ++j) {
                const float x = (hv[j] - mu) * rs * gv[j] + bv2[j];
                XT[(i * 4 + j) * LDP + t] = x / (1.f + __expf(-x));
            }
        }
    }
    __syncthreads();

    // ---- GEMM2: T = Hs @ M + cvec (64e x 224c), per-thread 8 edges x 7 strided cols
    const int eg = t >> 5;   // 0..7
    const int cg = t & 31;   // 0..31
    float acc[8][7];
    #pragma unroll
    for (int j = 0; j < 7; ++j) {
        const float cv = cvec[cg + 32 * j];
        #pragma unroll
        for (int i = 0; i < 8; ++i) acc[i][j] = cv;
    }
    for (int k = 0; k < FCn; ++k) {
        const float4 h0 = *(const float4*)&XT[k * LDP + eg * 8];
        const float4 h1 = *(const float4*)&XT[k * LDP + eg * 8 + 4];
        const float he[8] = {h0.x, h0.y, h0.z, h0.w, h1.x, h1.y, h1.z, h1.w};
        float m[7];
        #pragma unroll
        for (int j = 0; j < 7; ++j) m[j] = Mg[k * NCOL + cg + 32 * j];
        #pragma unroll
        for (int i = 0; i < 8; ++i)
            #pragma unroll
            for (int j = 0; j < 7; ++j)
                acc[i][j] += he[i] * m[j];
    }

    // ---- epilogue: register-run accumulation over sorted dsts, atomic flush per run
    float b0v[4];
    #pragma unroll
    for (int j = 0; j < 4; ++j) b0v[j] = b0s[cg + 32 * j];

    float run[15];
    #pragma unroll
    for (int r = 0; r < 15; ++r) run[r] = 0.f;
    int runDst = dsts_l[eg * 8];
    int runLen = 0;

    #pragma unroll
    for (int i = 0; i < 8; ++i) {
        const int li = eg * 8 + i;
        if (p0 + li >= E) break;
        const int d = dsts_l[li];
        if (d != runDst) {
            flushRun(out, runDst, cg, run, b0v, runLen);
            #pragma unroll
            for (int r = 0; r < 15; ++r) run[r] = 0.f;
            runLen = 0;
            runDst = d;
        }
        const float sh0 = Ea[li][0];
        const float s10 = Ea[li][1], s11 = Ea[li][2], s12 = Ea[li][3];
        #pragma unroll
        for (int j = 0; j < 4; ++j) run[j] = fmaf(sh0, acc[i][j], run[j]);
        const float t4 = acc[i][4], t5 = acc[i][5];
        run[4] = fmaf(t4, s10, run[4]);
        run[5] = fmaf(t4, s11, run[5]);
        run[6] = fmaf(t4, s12, run[6]);
        run[7] = fmaf(t5, s10, run[7]);
        run[8] = fmaf(t5, s11, run[8]);
        run[9] = fmaf(t5, s12, run[9]);
        const float t6 = acc[i][6];
        run[10] = fmaf(t6, Ea[li][4], run[10]);
        run[11] = fmaf(t6, Ea[li][5], run[11]);
        run[12] = fmaf(t6, Ea[li][6], run[12]);
        run[13] = fmaf(t6, Ea[li][7], run[13]);
        run[14] = fmaf(t6, Ea[li][8], run[14]);
        ++runLen;
    }
    if (runLen > 0 && runDst >= 0)
        flushRun(out, runDst, cg, run, b0v, runLen);
}

extern "C" void kernel_launch(void* const* d_in, const int* in_sizes, int n_in,
                              void* d_out, int out_size, void* d_ws, size_t ws_size,
                              hipStream_t stream)
{
    const float* edge_attr    = (const float*)d_in[1];
    const float* edge_scalars = (const float*)d_in[2];
    const int*   edge_dst     = (const int*)d_in[4];
    const float* exp_w     = (const float*)d_in[6];
    const float* exp_b     = (const float*)d_in[7];
    const float* rad_w1    = (const float*)d_in[8];
    const float* rad_b1    = (const float*)d_in[9];
    const float* rad_gamma = (const float*)d_in[10];
    const float* rad_beta  = (const float*)d_in[11];
    const float* rad_w2    = (const float*)d_in[12];
    const float* rad_b2    = (const float*)d_in[13];
    const float* proj_w0   = (const float*)d_in[14];
    const float* proj_b0   = (const float*)d_in[15];
    const float* proj_w1   = (const float*)d_in[16];
    const float* proj_w2   = (const float*)d_in[17];
    float* out = (float*)d_out;
    const int E = in_sizes[4];
    const int Nn = out_size / 480;

    // ws layout (all small)
    float* Mg   = (float*)d_ws;                 // 64*256
    float* cvec = Mg + FCn * NCOL;              // 256
    float* b0s  = cvec + NCOL;                  // 128
    int* off  = (int*)(b0s + 128);              // Nn+1
    int* cnt  = off + (Nn + 1);                 // Nn
    int* cur  = cnt + Nn;                       // Nn
    int* eids = cur + Nn;                       // E
    int* dsts = eids + E;                       // E

    precomp_kernel<<<FCn + 1, 256, 0, stream>>>(exp_w, exp_b, rad_w2, rad_b2,
                                                proj_w0, proj_b0, proj_w1, proj_w2,
                                                Mg, cvec, b0s);
    hipMemsetAsync(cnt, 0, (size_t)Nn * sizeof(int), stream);
    hipMemsetAsync(d_out, 0, (size_t)out_size * sizeof(float), stream);
    hist_kernel<<<512, 256, 0, stream>>>(edge_dst, cnt, E);
    scan_kernel<<<1, 256, 0, stream>>>(cnt, off, cur, Nn, E);
    scatter_kernel<<<512, 256, 0, stream>>>(edge_dst, cur, eids, dsts, E);
    const int blocks = (E + TEB - 1) / TEB;
    fused_kernel<<<blocks, 256, 0, stream>>>(edge_attr, edge_scalars, eids, dsts,
                                             rad_w1, rad_b1, rad_gamma, rad_beta,
                                             Mg, cvec, b0s, out, E);
}

// Round 5
// 573.608 us; speedup vs baseline: 1.1520x; 1.1520x over previous
//
#include <hip/hip_runtime.h>

#define FCn 64      // FC
#define NCOL 256    // padded Mg row stride (224 used)
#define TCOL 224    // stored T-columns per edge (exact, keeps gather linear)
#define TEB 64      // edges per block (pass 1)
#define LDP 68      // padded LDS row stride (floats)

// ---------------- precompute: fold s, rad_w2/rad_b2, proj_w*, 0.25 into M (64x224), cvec(224), b0s(128)
__global__ __launch_bounds__(256) void precomp_kernel(
    const float* __restrict__ exp_w, const float* __restrict__ exp_b,
    const float* __restrict__ rad_w2, const float* __restrict__ rad_b2,
    const float* __restrict__ proj_w0, const float* __restrict__ proj_b0,
    const float* __restrict__ proj_w1, const float* __restrict__ proj_w2,
    float* __restrict__ Mg, float* __restrict__ cvec, float* __restrict__ b0s)
{
    const int r = blockIdx.x;   // 0..63 -> M row r; 64 -> cvec/b0s
    const int c = threadIdx.x;  // 0..255
    const float* wrow = (r < FCn) ? (rad_w2 + (long long)r * 384) : rad_b2;
    float acc = 0.f;
    if (c < 128) {
        for (int q = 0; q < 128; ++q)
            acc += wrow[q] * (exp_w[q] + exp_b[q]) * proj_w0[q * 128 + c];
    } else if (c < 192) {
        const int d = c - 128;
        for (int q = 0; q < 128; ++q)
            acc += wrow[128 + q] * (exp_w[q] + exp_b[q]) * proj_w1[q * 64 + d];
    } else if (c < 224) {
        const int d = c - 192;
        for (int q = 0; q < 128; ++q)
            acc += wrow[256 + q] * (exp_w[q] + exp_b[q]) * proj_w2[q * 32 + d];
    }
    acc *= 0.25f;  // 1/sqrt(AVG_AGG)
    if (r < FCn) {
        Mg[r * NCOL + c] = acc;
    } else {
        cvec[c] = acc;
        if (c < 128) b0s[c] = 0.25f * proj_b0[c];
    }
}

// ---------------- CSR build
__global__ __launch_bounds__(256) void hist_kernel(const int* __restrict__ dst, int* __restrict__ cnt, int E)
{
    for (int e = blockIdx.x * 256 + threadIdx.x; e < E; e += gridDim.x * 256)
        atomicAdd(&cnt[dst[e]], 1);
}

__global__ __launch_bounds__(256) void scan_kernel(const int* __restrict__ cnt, int* __restrict__ off,
                                                   int* __restrict__ cur, int Nn, int Etot)
{
    __shared__ int part[256];
    __shared__ int spart[257];
    const int t = threadIdx.x;
    const int per = (Nn + 255) / 256;
    int s = 0;
    for (int i = 0; i < per; ++i) {
        const int idx = t * per + i;
        if (idx < Nn) s += cnt[idx];
    }
    part[t] = s;
    __syncthreads();
    if (t == 0) {
        int run = 0;
        spart[0] = 0;
        for (int i = 0; i < 256; ++i) { run += part[i]; spart[i + 1] = run; }
    }
    __syncthreads();
    int run = spart[t];
    for (int i = 0; i < per; ++i) {
        const int idx = t * per + i;
        if (idx < Nn) { off[idx] = run; cur[idx] = run; run += cnt[idx]; }
    }
    if (t == 0) off[Nn] = Etot;
}

__global__ __launch_bounds__(256) void scatter_kernel(const int* __restrict__ dst, int* __restrict__ cur,
                                                      int* __restrict__ eids, int E)
{
    for (int e = blockIdx.x * 256 + threadIdx.x; e < E; e += gridDim.x * 256) {
        const int pos = atomicAdd(&cur[dst[e]], 1);
        eids[pos] = e;
    }
}

// ---------------- pass 1: per-edge T (dst-sorted order) + sorted edge_attr copy
__global__ __launch_bounds__(256, 3) void compute_T_kernel(
    const float* __restrict__ edge_attr,    // E x 9
    const float* __restrict__ edge_scalars, // E x 64
    const int*   __restrict__ eids,         // E (sorted pos -> edge id)
    const float* __restrict__ rad_w1,       // 64 x 64
    const float* __restrict__ rad_b1,       // 64
    const float* __restrict__ rad_gamma,    // 64
    const float* __restrict__ rad_beta,     // 64
    const float* __restrict__ Mg,           // 64 x 256 (ws)
    const float* __restrict__ cvec,         // 256 (ws)
    float* __restrict__ T,                  // E x 224 (ws, sorted order)
    float* __restrict__ EaS,                // E x 9 (ws, sorted order) or nullptr
    int E)
{
    __shared__ float XT[FCn * LDP];   // [k][e]; reused as Hs^T after LN
    __shared__ float Hb[TEB * LDP];   // [e][c]
    __shared__ int   eids_l[TEB];
    const int t = threadIdx.x;
    const int p0 = blockIdx.x * TEB;

    if (t < TEB) eids_l[t] = (p0 + t < E) ? eids[p0 + t] : -1;
    __syncthreads();

    // ---- stage X^T (gathered 256B rows) + sorted edge_attr copy
    #pragma unroll
    for (int i = 0; i < 4; ++i) {
        const int idx = i * 256 + t;
        const int e  = idx >> 4;
        const int kq = idx & 15;
        const int eid = eids_l[e];
        float4 v = make_float4(0.f, 0.f, 0.f, 0.f);
        if (eid >= 0) v = *(const float4*)(edge_scalars + (long long)eid * FCn + kq * 4);
        XT[(kq * 4 + 0) * LDP + e] = v.x;
        XT[(kq * 4 + 1) * LDP + e] = v.y;
        XT[(kq * 4 + 2) * LDP + e] = v.z;
        XT[(kq * 4 + 3) * LDP + e] = v.w;
    }
    if (EaS) {
        #pragma unroll
        for (int i = 0; i < 3; ++i) {
            const int idx = i * 256 + t;
            if (idx < TEB * 9) {
                const int e = idx / 9, j = idx - e * 9;
                const int eid = eids_l[e];
                if (eid >= 0) EaS[(long long)(p0 + e) * 9 + j] = edge_attr[(long long)eid * 9 + j];
            }
        }
    }
    __syncthreads();

    // ---- GEMM1: H = X @ W1 + b1 (64e x 64c), per-thread 4x4
    {
        const int eg = t >> 4, cg = t & 15;
        float a[4][4];
        #pragma unroll
        for (int i = 0; i < 4; ++i)
            #pragma unroll
            for (int j = 0; j < 4; ++j) a[i][j] = 0.f;
        for (int k = 0; k < FCn; ++k) {
            const float4 xv = *(const float4*)&XT[k * LDP + eg * 4];
            const float4 wv = *(const float4*)&rad_w1[k * FCn + cg * 4];
            const float xe[4] = {xv.x, xv.y, xv.z, xv.w};
            const float wc[4] = {wv.x, wv.y, wv.z, wv.w};
            #pragma unroll
            for (int i = 0; i < 4; ++i)
                #pragma unroll
                for (int j = 0; j < 4; ++j)
                    a[i][j] += xe[i] * wc[j];
        }
        const float4 bv = *(const float4*)&rad_b1[cg * 4];
        const float bb[4] = {bv.x, bv.y, bv.z, bv.w};
        #pragma unroll
        for (int i = 0; i < 4; ++i) {
            float4 o;
            o.x = a[i][0] + bb[0]; o.y = a[i][1] + bb[1];
            o.z = a[i][2] + bb[2]; o.w = a[i][3] + bb[3];
            *(float4*)&Hb[(eg * 4 + i) * LDP + cg * 4] = o;
        }
    }
    __syncthreads();

    // ---- LayerNorm + silu, transpose into XT
    if (t < TEB) {
        const float4* hrow = (const float4*)&Hb[t * LDP];
        float4 r[16];
        float s1 = 0.f, s2 = 0.f;
        #pragma unroll
        for (int i = 0; i < 16; ++i) {
            r[i] = hrow[i];
            s1 += r[i].x + r[i].y + r[i].z + r[i].w;
            s2 += r[i].x * r[i].x + r[i].y * r[i].y + r[i].z * r[i].z + r[i].w * r[i].w;
        }
        const float mu  = s1 * (1.f / 64.f);
        const float var = s2 * (1.f / 64.f) - mu * mu;
        const float rs  = rsqrtf(var + 1e-5f);
        #pragma unroll
        for (int i = 0; i < 16; ++i) {
            const float4 g = *(const float4*)&rad_gamma[i * 4];
            const float4 b = *(const float4*)&rad_beta[i * 4];
            const float hv[4] = {r[i].x, r[i].y, r[i].z, r[i].w};
            const float gv[4] = {g.x, g.y, g.z, g.w};
            const float bv2[4] = {b.x, b.y, b.z, b.w};
            #pragma unroll
            for (int j = 0; j < 4; ++j) {
                const float x = (hv[j] - mu) * rs * gv[j] + bv2[j];
                XT[(i * 4 + j) * LDP + t] = x / (1.f + __expf(-x));
            }
        }
    }
    __syncthreads();

    // ---- GEMM2: T = Hs @ M + cvec (64e x 224c)
    //      per-thread: 8 edges x 8 CONTIGUOUS cols (cg<28 active) -> float4 Mg loads
    const int eg = t >> 5;   // 0..7
    const int cg = t & 31;   // 0..31 (only cg<28 carries cols)
    if (cg < 28) {
        const int c0 = cg * 8;
        float acc[8][8];
        {
            const float4 cv0 = *(const float4*)&cvec[c0];
            const float4 cv1 = *(const float4*)&cvec[c0 + 4];
            const float cv[8] = {cv0.x, cv0.y, cv0.z, cv0.w, cv1.x, cv1.y, cv1.z, cv1.w};
            #pragma unroll
            for (int i = 0; i < 8; ++i)
                #pragma unroll
                for (int j = 0; j < 8; ++j) acc[i][j] = cv[j];
        }
        for (int k = 0; k < FCn; ++k) {
            const float4 h0 = *(const float4*)&XT[k * LDP + eg * 8];
            const float4 h1 = *(const float4*)&XT[k * LDP + eg * 8 + 4];
            const float he[8] = {h0.x, h0.y, h0.z, h0.w, h1.x, h1.y, h1.z, h1.w};
            const float4 m0 = *(const float4*)&Mg[k * NCOL + c0];
            const float4 m1 = *(const float4*)&Mg[k * NCOL + c0 + 4];
            const float m[8] = {m0.x, m0.y, m0.z, m0.w, m1.x, m1.y, m1.z, m1.w};
            #pragma unroll
            for (int i = 0; i < 8; ++i)
                #pragma unroll
                for (int j = 0; j < 8; ++j)
                    acc[i][j] = fmaf(he[i], m[j], acc[i][j]);
        }
        #pragma unroll
        for (int i = 0; i < 8; ++i) {
            const int p = p0 + eg * 8 + i;
            if (p >= E) break;
            float* trow = T + (long long)p * TCOL + c0;
            float4 o0 = make_float4(acc[i][0], acc[i][1], acc[i][2], acc[i][3]);
            float4 o1 = make_float4(acc[i][4], acc[i][5], acc[i][6], acc[i][7]);
            *(float4*)trow = o0;
            *(float4*)(trow + 4) = o1;
        }
    }
}

// ---------------- pass 2: streaming gather, 1 node/block, zero float atomics
__global__ __launch_bounds__(512) void gather_kernel(
    const float* __restrict__ T,          // E x 224 (sorted)
    const float* __restrict__ EaS,        // E x 9 (sorted) or nullptr
    const float* __restrict__ edge_attr,  // E x 9 (fallback)
    const int*   __restrict__ eids,       // E (fallback)
    const int*   __restrict__ off,        // N+1
    const float* __restrict__ b0s,        // 128
    float* __restrict__ out)              // N x 480
{
    __shared__ __align__(16) float Trow[8 * TCOL];
    __shared__ float Ea2[8][12];
    __shared__ int   eids_l[8];
    const int n = blockIdx.x;
    const int t = threadIdx.x;
    const int beg = off[n], end = off[n + 1];

    // out col t -> (T col, edge_attr col)
    int tIdx = 0, eaIdx = 0;
    if (t < 128)      { tIdx = t;                        eaIdx = 0; }
    else if (t < 320) { const int idx = t - 128; tIdx = 128 + idx / 3; eaIdx = 1 + idx % 3; }
    else if (t < 480) { const int idx = t - 320; tIdx = 192 + idx / 5; eaIdx = 4 + idx % 5; }

    float acc = 0.f;
    for (int base = beg; base < end; base += 8) {
        const int m = min(8, end - base);
        if (t < 448) {
            // linear coalesced staging: float4 q of the m x 224 block
            if (t < m * 56)
                ((float4*)Trow)[t] = *(const float4*)(T + (long long)base * TCOL + t * 4);
        }
        if (EaS) {
            if (t >= 448) {
                // 64 threads cover 72 entries (two iterations for the first 8 threads)
                for (int i = t - 448; i < 72; i += 64) {
                    const int row = i / 9, j = i - row * 9;
                    if (row < m) Ea2[row][j] = EaS[(long long)(base + row) * 9 + j];
                }
            }
            __syncthreads();
        } else {
            const int i0 = t - 448;
            if (i0 >= 0 && i0 < 8 && i0 < m) eids_l[i0] = eids[base + i0];
            __syncthreads();
            if (t >= 448) {
                for (int i = t - 448; i < 72; i += 64) {
                    const int row = i / 9, j = i - row * 9;
                    if (row < m) Ea2[row][j] = edge_attr[(long long)eids_l[row] * 9 + j];
                }
            }
            __syncthreads();
        }
        #pragma unroll
        for (int i = 0; i < 8; ++i)
            if (i < m) acc = fmaf(Trow[i * TCOL + tIdx], Ea2[i][eaIdx], acc);
        __syncthreads();
    }

    if (t < 480) {
        float r = acc;
        if (t < 128) r += (float)(end - beg) * b0s[t];
        out[(long long)n * 480 + t] = r;
    }
}

extern "C" void kernel_launch(void* const* d_in, const int* in_sizes, int n_in,
                              void* d_out, int out_size, void* d_ws, size_t ws_size,
                              hipStream_t stream)
{
    const float* edge_attr    = (const float*)d_in[1];
    const float* edge_scalars = (const float*)d_in[2];
    const int*   edge_dst     = (const int*)d_in[4];
    const float* exp_w     = (const float*)d_in[6];
    const float* exp_b     = (const float*)d_in[7];
    const float* rad_w1    = (const float*)d_in[8];
    const float* rad_b1    = (const float*)d_in[9];
    const float* rad_gamma = (const float*)d_in[10];
    const float* rad_beta  = (const float*)d_in[11];
    const float* rad_w2    = (const float*)d_in[12];
    const float* rad_b2    = (const float*)d_in[13];
    const float* proj_w0   = (const float*)d_in[14];
    const float* proj_b0   = (const float*)d_in[15];
    const float* proj_w1   = (const float*)d_in[16];
    const float* proj_w2   = (const float*)d_in[17];
    float* out = (float*)d_out;
    const int E = in_sizes[4];
    const int Nn = out_size / 480;

    // ws layout: header, eids, T, (optional) EaS
    float* Mg   = (float*)d_ws;                 // 64*256
    float* cvec = Mg + FCn * NCOL;              // 256
    float* b0s  = cvec + NCOL;                  // 128
    int* off  = (int*)(b0s + 128);              // Nn+1
    int* cnt  = off + (Nn + 1);                 // Nn
    int* cur  = cnt + Nn;                       // Nn
    int* eids = cur + Nn;                       // E
    size_t tOff = (size_t)((char*)(eids + E) - (char*)d_ws);
    tOff = (tOff + 15) & ~(size_t)15;
    float* T = (float*)((char*)d_ws + tOff);    // E x 224 (sorted)
    size_t eaOff = tOff + (size_t)E * TCOL * sizeof(float);
    eaOff = (eaOff + 15) & ~(size_t)15;
    float* EaS = (float*)((char*)d_ws + eaOff); // E x 9 (sorted), optional
    const bool haveEa = (eaOff + (size_t)E * 9 * sizeof(float)) <= ws_size;
    if (!haveEa) EaS = nullptr;

    precomp_kernel<<<FCn + 1, 256, 0, stream>>>(exp_w, exp_b, rad_w2, rad_b2,
                                                proj_w0, proj_b0, proj_w1, proj_w2,
                                                Mg, cvec, b0s);
    hipMemsetAsync(cnt, 0, (size_t)Nn * sizeof(int), stream);
    hist_kernel<<<512, 256, 0, stream>>>(edge_dst, cnt, E);
    scan_kernel<<<1, 256, 0, stream>>>(cnt, off, cur, Nn, E);
    scatter_kernel<<<512, 256, 0, stream>>>(edge_dst, cur, eids, E);

    const int blocks = (E + TEB - 1) / TEB;
    compute_T_kernel<<<blocks, 256, 0, stream>>>(edge_attr, edge_scalars, eids,
                                                 rad_w1, rad_b1, rad_gamma, rad_beta,
                                                 Mg, cvec, T, EaS, E);
    gather_kernel<<<Nn, 512, 0, stream>>>(T, EaS, edge_attr, eids, off, b0s, out);
}